// Round 2
// baseline (152661.475 us; speedup 1.0000x reference)
//
#include <hip/hip_runtime.h>

// ---------------- problem dims ----------------
constexpr int BB = 16;       // batch
constexpr int TT = 256;      // seq len
constexpr int IN0 = 512;     // input dim (layer 0)
constexpr int HH = 1024;     // hidden
constexpr int GG = 4096;     // 4*H gates
constexpr int NLAYERS = 8;
constexpr int NWG = 256;     // scan workgroups (1 per CU)

// ---------------- ws layout (bytes) ----------------
constexpr size_t XG_OFF  = 0;                        // xg2 [t][b][4096] : 64 MB
constexpr size_t HSA_OFF = 67108864;                 // 16 MB
constexpr size_t HSB_OFF = HSA_OFF + 16777216;       // 16 MB
constexpr size_t HG2_OFF = HSB_OFF + 16777216;       // hglob2 [16 chunk][16 b][64] : 64 KB
constexpr size_t FC1_OFF = HG2_OFF + 65536;          // 32 KB
constexpr size_t FC2_OFF = FC1_OFF + 32768;          // 16 KB
constexpr size_t BAR_OFF = FC2_OFF + 16384;          // gdone: 16 counters @ 64B stride

// ---------------- scan LDS float offsets ----------------
// Wt: row r base = r*1088 + 8*(r>>2); block kb at +68*kb  (bank-spread)
// Hb: chunk B base = HB_F + B*1092; batch b at +68*b      (bank-spread)
constexpr int WT_F = 0;        // 17440 floats
constexpr int HB_F = 17440;    // 17472 floats
constexpr int PART_F = 34912;  // 1024 floats  [wave][16r][16b]
constexpr int GV_F = 35936;    // 256 floats   [16r][16b]
constexpr int SMEM_FLOATS = 36192;
constexpr int SMEM_BYTES = SMEM_FLOATS * 4;   // 144,768 B

// ---------------- GEMM: xg2[(t*16+b)*4096+n] = X[m]·W[n] + bih[n]+bhh[n], m=b*256+t
__global__ __launch_bounds__(256) void gemm_xg(const float* __restrict__ X,
                                               const float* __restrict__ W,
                                               const float* __restrict__ bih,
                                               const float* __restrict__ bhh,
                                               float* __restrict__ out, int K)
{
    __shared__ float Xs[64][33];
    __shared__ float Ws[64][33];
    const int tid = threadIdx.x;
    const int tm = tid >> 4, tn = tid & 15;
    const int m0 = blockIdx.y * 64, n0 = blockIdx.x * 64;
    float acc[4][4] = {};

    for (int k0 = 0; k0 < K; k0 += 32) {
#pragma unroll
        for (int i = 0; i < 2; ++i) {
            int f = tid + i * 256;
            int row = f >> 3, c4 = (f & 7) << 2;
            float4 xv = *(const float4*)(X + (size_t)(m0 + row) * K + k0 + c4);
            float4 wv = *(const float4*)(W + (size_t)(n0 + row) * K + k0 + c4);
            Xs[row][c4 + 0] = xv.x; Xs[row][c4 + 1] = xv.y;
            Xs[row][c4 + 2] = xv.z; Xs[row][c4 + 3] = xv.w;
            Ws[row][c4 + 0] = wv.x; Ws[row][c4 + 1] = wv.y;
            Ws[row][c4 + 2] = wv.z; Ws[row][c4 + 3] = wv.w;
        }
        __syncthreads();
#pragma unroll 4
        for (int kk = 0; kk < 32; ++kk) {
            float xr[4], wc[4];
#pragma unroll
            for (int i = 0; i < 4; ++i) xr[i] = Xs[tm * 4 + i][kk];
#pragma unroll
            for (int j = 0; j < 4; ++j) wc[j] = Ws[tn * 4 + j][kk];
#pragma unroll
            for (int i = 0; i < 4; ++i)
#pragma unroll
                for (int j = 0; j < 4; ++j)
                    acc[i][j] = fmaf(xr[i], wc[j], acc[i][j]);
        }
        __syncthreads();
    }

    const int n = n0 + tn * 4;
    const float4 bi = *(const float4*)(bih + n);
    const float4 bh = *(const float4*)(bhh + n);
    const float4 bias = {bi.x + bh.x, bi.y + bh.y, bi.z + bh.z, bi.w + bh.w};
#pragma unroll
    for (int i = 0; i < 4; ++i) {
        int m = m0 + tm * 4 + i;
        int bb = m >> 8, tt = m & 255;
        float4 o = {acc[i][0] + bias.x, acc[i][1] + bias.y,
                    acc[i][2] + bias.z, acc[i][3] + bias.w};
        *(float4*)(out + (size_t)(tt * 16 + bb) * GG + n) = o;
    }
}

__device__ __forceinline__ float sigf(float x) { return 1.0f / (1.0f + expf(-x)); }

__device__ __forceinline__ void wait_ge(unsigned* p, unsigned want)
{
    while (__hip_atomic_load(p, __ATOMIC_ACQUIRE, __HIP_MEMORY_SCOPE_AGENT) < want)
        __builtin_amdgcn_s_sleep(1);
}

// ---------------- per-layer LSTM scan (persistent, flag-synced) ----------------
// WG wg owns h-cols j0=4wg..4wg+3 -> 16 gate rows grow(r)=(r>>2)*1024+j0+(r&3)
// wave w handles k in [256w,256w+256) = chunks 4w..4w+3; lane: kg=ln>>4, rg=(ln>>2)&3, bg=ln&3
__global__ __launch_bounds__(256, 1) void lstm_scan(const float* __restrict__ Whh,
                                                    const float* __restrict__ xg,
                                                    float* __restrict__ hseq,
                                                    float* __restrict__ hglob2,
                                                    unsigned* __restrict__ gdone,
                                                    unsigned wantbase)
{
    extern __shared__ float smem[];
    float4* sm4 = (float4*)smem;

    const int tid = threadIdx.x;
    const int wg  = blockIdx.x;
    const int j0  = wg << 2;
    const int w   = tid >> 6;
    const int ln  = tid & 63;

    // ---- stage Whh tile once: 16 iters, one float4/thread, coalesced 256B runs
    {
        const int r = tid >> 4, m = tid & 15;
        const int grow = ((r >> 2) << 10) + j0 + (r & 3);
        const float4* wsrc = (const float4*)Whh + (size_t)grow * 256 + m;
        float4* wdst = sm4 + r * 272 + 2 * (r >> 2) + m;
#pragma unroll
        for (int q = 0; q < 16; ++q)
            wdst[q * 17] = wsrc[q * 16];
    }

    // lane decomposition
    const int kg = ln >> 4, rg = (ln >> 2) & 3, bg4 = ln & 3;
    const int blk = (w << 2) + kg;               // global chunk 0..15
    // dot fragment bases (float4 indices)
    int Wb[4], Hb[4];
#pragma unroll
    for (int i = 0; i < 4; ++i)
        Wb[i] = (4 * rg + i) * 272 + 2 * rg + blk * 17;
#pragma unroll
    for (int j = 0; j < 4; ++j)
        Hb[j] = (HB_F >> 2) + blk * 273 + (4 * bg4 + j) * 17;

    // staging lane mapping
    const int sb_hi = ln >> 4, sm_lo = ln & 15;

    // reduce / gate thread mapping (as round-1, verified)
    const int r_red = tid >> 4, b_red = tid & 15;
    const int grow_red = ((r_red >> 2) << 10) + j0 + (r_red & 3);
    const int jl = tid >> 4, bg = tid & 15;      // for tid<64

    unsigned* mygd = gdone + ((wg >> 4) << 4);

    float c_state = 0.0f;
    __syncthreads();

    for (int t = 0; t < TT; ++t) {
        float xg_pref = xg[(size_t)(t * 16 + b_red) * GG + grow_red];
        float acc[4][4] = {};

        if (t > 0) {
            const unsigned want = wantbase + 16u * (unsigned)t;
            // wait for the 4 producer groups this wave consumes
#pragma unroll
            for (int c = 0; c < 4; ++c)
                wait_ge(gdone + (((w << 2) + c) << 4), want);
            __threadfence();   // acquire: invalidate L1 before reading fresh h

            // global -> regs (all 16 loads in flight) -> LDS
            float4 v[4][4];
#pragma unroll
            for (int c = 0; c < 4; ++c)
#pragma unroll
                for (int i = 0; i < 4; ++i)
                    v[c][i] = *((const float4*)hglob2 + ((w << 2) + c) * 256 + (i << 6) + ln);
#pragma unroll
            for (int c = 0; c < 4; ++c)
#pragma unroll
                for (int i = 0; i < 4; ++i)
                    sm4[(HB_F >> 2) + ((w << 2) + c) * 273 + ((i << 2) + sb_hi) * 17 + sm_lo] = v[c][i];
            asm volatile("s_waitcnt lgkmcnt(0)" ::: "memory");
            __builtin_amdgcn_wave_barrier();

            // ---- dot: 16 k4-iters, 8 b128 reads + 64 fma each
#pragma unroll 4
            for (int k4 = 0; k4 < 16; ++k4) {
                float4 wv[4], hv[4];
#pragma unroll
                for (int i = 0; i < 4; ++i) wv[i] = sm4[Wb[i] + k4];
#pragma unroll
                for (int j = 0; j < 4; ++j) hv[j] = sm4[Hb[j] + k4];
#pragma unroll
                for (int i = 0; i < 4; ++i)
#pragma unroll
                    for (int j = 0; j < 4; ++j) {
                        acc[i][j] = fmaf(wv[i].x, hv[j].x, acc[i][j]);
                        acc[i][j] = fmaf(wv[i].y, hv[j].y, acc[i][j]);
                        acc[i][j] = fmaf(wv[i].z, hv[j].z, acc[i][j]);
                        acc[i][j] = fmaf(wv[i].w, hv[j].w, acc[i][j]);
                    }
            }
            // ---- k-butterfly across kg (lane bits 4,5)
#pragma unroll
            for (int i = 0; i < 4; ++i)
#pragma unroll
                for (int j = 0; j < 4; ++j) {
                    float vv = acc[i][j];
                    vv += __shfl_xor(vv, 16);
                    vv += __shfl_xor(vv, 32);
                    acc[i][j] = vv;
                }
        }

        if (ln < 16) {   // kg==0 lanes hold full per-wave k-slice sums
            const int rg0 = ln >> 2, bg0 = ln & 3;
#pragma unroll
            for (int i = 0; i < 4; ++i)
#pragma unroll
                for (int j = 0; j < 4; ++j)
                    smem[PART_F + (w << 8) + (4 * rg0 + i) * 16 + 4 * bg0 + j] = acc[i][j];
        }
        __syncthreads();

        smem[GV_F + tid] = smem[PART_F + tid] + smem[PART_F + 256 + tid] +
                           smem[PART_F + 512 + tid] + smem[PART_F + 768 + tid] + xg_pref;
        __syncthreads();

        float hval = 0.f;
        int col = 0;
        if (tid < 64) {
            col = j0 + jl;
            float iv = smem[GV_F + (jl     ) * 16 + bg];
            float fv = smem[GV_F + (jl +  4) * 16 + bg];
            float gg = smem[GV_F + (jl +  8) * 16 + bg];
            float ov = smem[GV_F + (jl + 12) * 16 + bg];
            c_state = sigf(fv) * c_state + sigf(iv) * tanhf(gg);
            hval = sigf(ov) * tanhf(c_state);
            hglob2[((col >> 6) << 10) + (bg << 6) + (col & 63)] = hval;
        }
        __syncthreads();
        if (tid == 0) {
            __threadfence();   // release: drain hglob2 stores (barrier drained waves)
            __hip_atomic_fetch_add(mygd, 1u, __ATOMIC_RELEASE, __HIP_MEMORY_SCOPE_AGENT);
        }
        if (tid < 64)          // off critical path: next-layer GEMM input
            hseq[(size_t)(bg * TT + t) * HH + col] = hval;
    }
}

// ---------------- FC head ----------------
__global__ void fc_relu(const float* __restrict__ in, const float* __restrict__ w,
                        const float* __restrict__ b, float* __restrict__ out,
                        int N, int K, int instride, int do_relu)
{
    int g = blockIdx.x * blockDim.x + threadIdx.x;
    if (g >= BB * N) return;
    int bi = g / N, n = g - bi * N;
    const float* ip = in + (size_t)bi * instride;
    const float* wp = w + (size_t)n * K;
    float s = 0.f;
    for (int k = 0; k < K; k += 4) {
        float4 a = *(const float4*)(ip + k);
        float4 q = *(const float4*)(wp + k);
        s += a.x * q.x + a.y * q.y + a.z * q.z + a.w * q.w;
    }
    s += b[n];
    if (do_relu) s = fmaxf(s, 0.f);
    out[g] = s;
}

// ---------------- launch ----------------
extern "C" void kernel_launch(void* const* d_in, const int* in_sizes, int n_in,
                              void* d_out, int out_size, void* d_ws, size_t ws_size,
                              hipStream_t stream)
{
    const float* x    = (const float*)d_in[0];
    const float* Wih0 = (const float*)d_in[1];
    const float* WihR = (const float*)d_in[2];
    const float* Whh  = (const float*)d_in[3];
    const float* bih  = (const float*)d_in[4];
    const float* bhh  = (const float*)d_in[5];
    const float* fc1w = (const float*)d_in[6];
    const float* fc1b = (const float*)d_in[7];
    const float* fc2w = (const float*)d_in[8];
    const float* fc2b = (const float*)d_in[9];
    const float* fc3w = (const float*)d_in[10];
    const float* fc3b = (const float*)d_in[11];
    float* out = (float*)d_out;
    char* ws = (char*)d_ws;

    float* xg     = (float*)(ws + XG_OFF);
    float* hsA    = (float*)(ws + HSA_OFF);
    float* hsB    = (float*)(ws + HSB_OFF);
    float* hglob2 = (float*)(ws + HG2_OFF);
    float* fc1o   = (float*)(ws + FC1_OFF);
    float* fc2o   = (float*)(ws + FC2_OFF);
    unsigned* gdone = (unsigned*)(ws + BAR_OFF);

    hipFuncSetAttribute((const void*)lstm_scan,
                        hipFuncAttributeMaxDynamicSharedMemorySize, SMEM_BYTES);
    hipMemsetAsync(ws + BAR_OFF, 0, 4096, stream);   // flags = 0 (monotonic across layers)

    for (int l = 0; l < NLAYERS; ++l) {
        const float* X  = (l == 0) ? x : ((l & 1) ? hsA : hsB);
        const int K     = (l == 0) ? IN0 : HH;
        const float* Wl = (l == 0) ? Wih0 : (WihR + (size_t)(l - 1) * GG * HH);
        gemm_xg<<<dim3(GG / 64, (BB * TT) / 64), 256, 0, stream>>>(
            X, Wl, bih + (size_t)l * GG, bhh + (size_t)l * GG, xg, K);

        float* hout = (l & 1) ? hsB : hsA;
        const float* whh_l = Whh + (size_t)l * GG * HH;
        unsigned wantbase = (unsigned)(16 * TT * l);
        void* args[6] = {(void*)&whh_l, (void*)&xg, (void*)&hout,
                         (void*)&hglob2, (void*)&gdone, (void*)&wantbase};
        hipError_t e = hipLaunchCooperativeKernel((void*)lstm_scan, dim3(NWG), dim3(256),
                                                  args, SMEM_BYTES, stream);
        if (e != hipSuccess) {
            lstm_scan<<<dim3(NWG), dim3(256), SMEM_BYTES, stream>>>(
                whh_l, xg, hout, hglob2, gdone, wantbase);
        }
    }

    // FC head reads layer-7 output's last timestep straight from hseq (hsB)
    const float* hlast = hsB + (size_t)255 * HH;
    fc_relu<<<32, 256, 0, stream>>>(hlast, fc1w, fc1b, fc1o, 512, 1024, TT * HH, 1);
    fc_relu<<<16, 256, 0, stream>>>(fc1o, fc2w, fc2b, fc2o, 256, 512, 512, 1);
    fc_relu<<<1, 16, 0, stream>>>(fc2o, fc3w, fc3b, out, 1, 256, 256, 0);
}

// Round 3
// 55664.343 us; speedup vs baseline: 2.7425x; 2.7425x over previous
//
#include <hip/hip_runtime.h>

// ---------------- problem dims ----------------
constexpr int BB = 16;       // batch
constexpr int TT = 256;      // seq len
constexpr int IN0 = 512;     // input dim (layer 0)
constexpr int HH = 1024;     // hidden
constexpr int GG = 4096;     // 4*H gates
constexpr int NLAYERS = 8;
constexpr int NWG = 256;     // scan workgroups (1 per CU)

// ---------------- ws layout (bytes) ----------------
constexpr size_t XG_OFF  = 0;                        // xg2 [t][b][4096] : 64 MB
constexpr size_t HSA_OFF = 67108864;                 // 16 MB
constexpr size_t HSB_OFF = HSA_OFF + 16777216;       // 16 MB
constexpr size_t HG2_OFF = HSB_OFF + 16777216;       // hglob2 [16 chunk][16 b][64] : 64 KB
constexpr size_t FC1_OFF = HG2_OFF + 65536;          // 32 KB
constexpr size_t FC2_OFF = FC1_OFF + 32768;          // 16 KB
constexpr size_t BAR_OFF = FC2_OFF + 16384;          // barrier state (4 KB)
// bar layout (unsigned): arrive[g] at g*16 (g=0..15); root at 256;
//                        gen copy[g] at 512 + g*16   (all 64B-stride lines)

// ---------------- scan LDS float offsets ----------------
constexpr int WT_F = 0;        // 17440 floats
constexpr int HB_F = 17440;    // 17472 floats
constexpr int PART_F = 34912;  // 1024 floats  [wave][16r][16b]
constexpr int GV_F = 35936;    // 256 floats   [16r][16b]
constexpr int SMEM_FLOATS = 36192;
constexpr int SMEM_BYTES = SMEM_FLOATS * 4;   // 144,768 B

// ---------------- GEMM: xg2[(t*16+b)*4096+n] = X[m]·W[n] + bih[n]+bhh[n], m=b*256+t
__global__ __launch_bounds__(256) void gemm_xg(const float* __restrict__ X,
                                               const float* __restrict__ W,
                                               const float* __restrict__ bih,
                                               const float* __restrict__ bhh,
                                               float* __restrict__ out, int K)
{
    __shared__ float Xs[64][33];
    __shared__ float Ws[64][33];
    const int tid = threadIdx.x;
    const int tm = tid >> 4, tn = tid & 15;
    const int m0 = blockIdx.y * 64, n0 = blockIdx.x * 64;
    float acc[4][4] = {};

    for (int k0 = 0; k0 < K; k0 += 32) {
#pragma unroll
        for (int i = 0; i < 2; ++i) {
            int f = tid + i * 256;
            int row = f >> 3, c4 = (f & 7) << 2;
            float4 xv = *(const float4*)(X + (size_t)(m0 + row) * K + k0 + c4);
            float4 wv = *(const float4*)(W + (size_t)(n0 + row) * K + k0 + c4);
            Xs[row][c4 + 0] = xv.x; Xs[row][c4 + 1] = xv.y;
            Xs[row][c4 + 2] = xv.z; Xs[row][c4 + 3] = xv.w;
            Ws[row][c4 + 0] = wv.x; Ws[row][c4 + 1] = wv.y;
            Ws[row][c4 + 2] = wv.z; Ws[row][c4 + 3] = wv.w;
        }
        __syncthreads();
#pragma unroll 4
        for (int kk = 0; kk < 32; ++kk) {
            float xr[4], wc[4];
#pragma unroll
            for (int i = 0; i < 4; ++i) xr[i] = Xs[tm * 4 + i][kk];
#pragma unroll
            for (int j = 0; j < 4; ++j) wc[j] = Ws[tn * 4 + j][kk];
#pragma unroll
            for (int i = 0; i < 4; ++i)
#pragma unroll
                for (int j = 0; j < 4; ++j)
                    acc[i][j] = fmaf(xr[i], wc[j], acc[i][j]);
        }
        __syncthreads();
    }

    const int n = n0 + tn * 4;
    const float4 bi = *(const float4*)(bih + n);
    const float4 bh = *(const float4*)(bhh + n);
    const float4 bias = {bi.x + bh.x, bi.y + bh.y, bi.z + bh.z, bi.w + bh.w};
#pragma unroll
    for (int i = 0; i < 4; ++i) {
        int m = m0 + tm * 4 + i;
        int bb = m >> 8, tt = m & 255;
        float4 o = {acc[i][0] + bias.x, acc[i][1] + bias.y,
                    acc[i][2] + bias.z, acc[i][3] + bias.w};
        *(float4*)(out + (size_t)(tt * 16 + bb) * GG + n) = o;
    }
}

__device__ __forceinline__ float sigf(float x) { return 1.0f / (1.0f + expf(-x)); }

// ---------------- grid barrier: tree arrive + 16-way-spread gen, tid0-only ----------------
// RELAXED poll (no per-iteration cache invalidation!), single full fence after detect.
__device__ __forceinline__ void grid_barrier(unsigned* bar, int wg, unsigned target)
{
    __syncthreads();
    if (threadIdx.x == 0) {
        __threadfence();   // release: make this WG's hglob2 stores agent-visible
        unsigned* arr  = bar + ((wg >> 4) << 4);
        unsigned* root = bar + 256;
        unsigned* genc = bar + 512 + ((wg >> 4) << 4);
        unsigned a = __hip_atomic_fetch_add(arr, 1u, __ATOMIC_RELAXED, __HIP_MEMORY_SCOPE_AGENT);
        if (a == 15u) {
            unsigned ra = __hip_atomic_fetch_add(root, 1u, __ATOMIC_RELAXED, __HIP_MEMORY_SCOPE_AGENT);
            if (ra == 15u) {
                __hip_atomic_store(root, 0u, __ATOMIC_RELAXED, __HIP_MEMORY_SCOPE_AGENT);
#pragma unroll
                for (int i = 0; i < 16; ++i)
                    __hip_atomic_store(bar + (i << 4), 0u, __ATOMIC_RELAXED, __HIP_MEMORY_SCOPE_AGENT);
#pragma unroll
                for (int i = 0; i < 16; ++i)
                    __hip_atomic_store(bar + 512 + (i << 4), target,
                                       __ATOMIC_RELEASE, __HIP_MEMORY_SCOPE_AGENT);
            }
        }
        while (__hip_atomic_load(genc, __ATOMIC_RELAXED, __HIP_MEMORY_SCOPE_AGENT) < target)
            __builtin_amdgcn_s_sleep(2);
        __threadfence();   // acquire: invalidate stale cached h before next broadcast
    }
    __syncthreads();
}

// ---------------- per-layer LSTM scan (persistent, barrier-synced) ----------------
// WG wg owns h-cols j0=4wg..4wg+3 -> 16 gate rows grow(r)=(r>>2)*1024+j0+(r&3)
// wave w handles k in [256w,256w+256) = chunks 4w..4w+3; lane: kg=ln>>4, rg=(ln>>2)&3, bg=ln&3
__global__ __launch_bounds__(256, 1) void lstm_scan(const float* __restrict__ Whh,
                                                    const float* __restrict__ xg,
                                                    float* __restrict__ hseq,
                                                    float* __restrict__ hglob2,
                                                    unsigned* __restrict__ bar,
                                                    unsigned wantbase)
{
    extern __shared__ float smem[];
    float4* sm4 = (float4*)smem;

    const int tid = threadIdx.x;
    const int wg  = blockIdx.x;
    const int j0  = wg << 2;
    const int w   = tid >> 6;
    const int ln  = tid & 63;

    // ---- stage Whh tile once: 16 iters, one float4/thread, coalesced 256B runs
    {
        const int r = tid >> 4, m = tid & 15;
        const int grow = ((r >> 2) << 10) + j0 + (r & 3);
        const float4* wsrc = (const float4*)Whh + (size_t)grow * 256 + m;
        float4* wdst = sm4 + r * 272 + 2 * (r >> 2) + m;
#pragma unroll
        for (int q = 0; q < 16; ++q)
            wdst[q * 17] = wsrc[q * 16];
    }

    // lane decomposition
    const int kg = ln >> 4, rg = (ln >> 2) & 3, bg4 = ln & 3;
    const int blk = (w << 2) + kg;               // global chunk 0..15
    int Wb[4], Hb[4];
#pragma unroll
    for (int i = 0; i < 4; ++i)
        Wb[i] = (4 * rg + i) * 272 + 2 * rg + blk * 17;
#pragma unroll
    for (int j = 0; j < 4; ++j)
        Hb[j] = (HB_F >> 2) + blk * 273 + (4 * bg4 + j) * 17;

    const int sb_hi = ln >> 4, sm_lo = ln & 15;

    const int r_red = tid >> 4, b_red = tid & 15;
    const int grow_red = ((r_red >> 2) << 10) + j0 + (r_red & 3);
    const int jl = tid >> 4, bg = tid & 15;      // for tid<64

    float c_state = 0.0f;
    __syncthreads();

    float xg_pref = xg[(size_t)(0 * 16 + b_red) * GG + grow_red];

    for (int t = 0; t < TT; ++t) {
        float acc[4][4] = {};

        if (t > 0) {
            // h(t-1) published by previous barrier: global -> regs -> LDS
            float4 v[4][4];
#pragma unroll
            for (int c = 0; c < 4; ++c)
#pragma unroll
                for (int i = 0; i < 4; ++i)
                    v[c][i] = *((const float4*)hglob2 + ((w << 2) + c) * 256 + (i << 6) + ln);
#pragma unroll
            for (int c = 0; c < 4; ++c)
#pragma unroll
                for (int i = 0; i < 4; ++i)
                    sm4[(HB_F >> 2) + ((w << 2) + c) * 273 + ((i << 2) + sb_hi) * 17 + sm_lo] = v[c][i];
            asm volatile("s_waitcnt lgkmcnt(0)" ::: "memory");
            __builtin_amdgcn_wave_barrier();

            // ---- dot: 16 k4-iters, 8 b128 reads + 64 fma each
#pragma unroll 4
            for (int k4 = 0; k4 < 16; ++k4) {
                float4 wv[4], hv[4];
#pragma unroll
                for (int i = 0; i < 4; ++i) wv[i] = sm4[Wb[i] + k4];
#pragma unroll
                for (int j = 0; j < 4; ++j) hv[j] = sm4[Hb[j] + k4];
#pragma unroll
                for (int i = 0; i < 4; ++i)
#pragma unroll
                    for (int j = 0; j < 4; ++j) {
                        acc[i][j] = fmaf(wv[i].x, hv[j].x, acc[i][j]);
                        acc[i][j] = fmaf(wv[i].y, hv[j].y, acc[i][j]);
                        acc[i][j] = fmaf(wv[i].z, hv[j].z, acc[i][j]);
                        acc[i][j] = fmaf(wv[i].w, hv[j].w, acc[i][j]);
                    }
            }
            // ---- k-butterfly across kg (lane bits 4,5)
#pragma unroll
            for (int i = 0; i < 4; ++i)
#pragma unroll
                for (int j = 0; j < 4; ++j) {
                    float vv = acc[i][j];
                    vv += __shfl_xor(vv, 16);
                    vv += __shfl_xor(vv, 32);
                    acc[i][j] = vv;
                }
        }

        if (ln < 16) {   // kg==0 lanes hold full per-wave k-slice sums
            const int rg0 = ln >> 2, bg0 = ln & 3;
#pragma unroll
            for (int i = 0; i < 4; ++i)
#pragma unroll
                for (int j = 0; j < 4; ++j)
                    smem[PART_F + (w << 8) + (4 * rg0 + i) * 16 + 4 * bg0 + j] = acc[i][j];
        }
        __syncthreads();

        smem[GV_F + tid] = smem[PART_F + tid] + smem[PART_F + 256 + tid] +
                           smem[PART_F + 512 + tid] + smem[PART_F + 768 + tid] + xg_pref;
        __syncthreads();

        // prefetch next step's xg now: latency hides under gates + barrier
        float xg_next = 0.f;
        if (t + 1 < TT)
            xg_next = xg[(size_t)((t + 1) * 16 + b_red) * GG + grow_red];

        if (tid < 64) {
            const int col = j0 + jl;
            float iv = smem[GV_F + (jl     ) * 16 + bg];
            float fv = smem[GV_F + (jl +  4) * 16 + bg];
            float gg = smem[GV_F + (jl +  8) * 16 + bg];
            float ov = smem[GV_F + (jl + 12) * 16 + bg];
            c_state = sigf(fv) * c_state + sigf(iv) * tanhf(gg);
            float hval = sigf(ov) * tanhf(c_state);
            hglob2[((col >> 6) << 10) + (bg << 6) + (col & 63)] = hval;
            hseq[(size_t)(bg * TT + t) * HH + col] = hval;
        }

        if (t < TT - 1)
            grid_barrier(bar, wg, wantbase + (unsigned)t + 1u);
        xg_pref = xg_next;
    }
}

// ---------------- FC head ----------------
__global__ void fc_relu(const float* __restrict__ in, const float* __restrict__ w,
                        const float* __restrict__ b, float* __restrict__ out,
                        int N, int K, int instride, int do_relu)
{
    int g = blockIdx.x * blockDim.x + threadIdx.x;
    if (g >= BB * N) return;
    int bi = g / N, n = g - bi * N;
    const float* ip = in + (size_t)bi * instride;
    const float* wp = w + (size_t)n * K;
    float s = 0.f;
    for (int k = 0; k < K; k += 4) {
        float4 a = *(const float4*)(ip + k);
        float4 q = *(const float4*)(wp + k);
        s += a.x * q.x + a.y * q.y + a.z * q.z + a.w * q.w;
    }
    s += b[n];
    if (do_relu) s = fmaxf(s, 0.f);
    out[g] = s;
}

// ---------------- launch ----------------
extern "C" void kernel_launch(void* const* d_in, const int* in_sizes, int n_in,
                              void* d_out, int out_size, void* d_ws, size_t ws_size,
                              hipStream_t stream)
{
    const float* x    = (const float*)d_in[0];
    const float* Wih0 = (const float*)d_in[1];
    const float* WihR = (const float*)d_in[2];
    const float* Whh  = (const float*)d_in[3];
    const float* bih  = (const float*)d_in[4];
    const float* bhh  = (const float*)d_in[5];
    const float* fc1w = (const float*)d_in[6];
    const float* fc1b = (const float*)d_in[7];
    const float* fc2w = (const float*)d_in[8];
    const float* fc2b = (const float*)d_in[9];
    const float* fc3w = (const float*)d_in[10];
    const float* fc3b = (const float*)d_in[11];
    float* out = (float*)d_out;
    char* ws = (char*)d_ws;

    float* xg     = (float*)(ws + XG_OFF);
    float* hsA    = (float*)(ws + HSA_OFF);
    float* hsB    = (float*)(ws + HSB_OFF);
    float* hglob2 = (float*)(ws + HG2_OFF);
    float* fc1o   = (float*)(ws + FC1_OFF);
    float* fc2o   = (float*)(ws + FC2_OFF);
    unsigned* bar = (unsigned*)(ws + BAR_OFF);

    hipFuncSetAttribute((const void*)lstm_scan,
                        hipFuncAttributeMaxDynamicSharedMemorySize, SMEM_BYTES);
    hipMemsetAsync(ws + BAR_OFF, 0, 4096, stream);   // arrive/root/gen = 0 (monotonic)

    for (int l = 0; l < NLAYERS; ++l) {
        const float* X  = (l == 0) ? x : ((l & 1) ? hsA : hsB);
        const int K     = (l == 0) ? IN0 : HH;
        const float* Wl = (l == 0) ? Wih0 : (WihR + (size_t)(l - 1) * GG * HH);
        gemm_xg<<<dim3(GG / 64, (BB * TT) / 64), 256, 0, stream>>>(
            X, Wl, bih + (size_t)l * GG, bhh + (size_t)l * GG, xg, K);

        float* hout = (l & 1) ? hsB : hsA;
        const float* whh_l = Whh + (size_t)l * GG * HH;
        unsigned wantbase = (unsigned)(TT * l);
        void* args[6] = {(void*)&whh_l, (void*)&xg, (void*)&hout,
                         (void*)&hglob2, (void*)&bar, (void*)&wantbase};
        hipError_t e = hipLaunchCooperativeKernel((void*)lstm_scan, dim3(NWG), dim3(256),
                                                  args, SMEM_BYTES, stream);
        if (e != hipSuccess) {
            lstm_scan<<<dim3(NWG), dim3(256), SMEM_BYTES, stream>>>(
                whh_l, xg, hout, hglob2, bar, wantbase);
        }
    }

    const float* hlast = hsB + (size_t)255 * HH;
    fc_relu<<<32, 256, 0, stream>>>(hlast, fc1w, fc1b, fc1o, 512, 1024, TT * HH, 1);
    fc_relu<<<16, 256, 0, stream>>>(fc1o, fc2w, fc2b, fc2o, 256, 512, 512, 1);
    fc_relu<<<1, 16, 0, stream>>>(fc2o, fc3w, fc3b, out, 1, 256, 256, 0);
}

// Round 5
// 18752.193 us; speedup vs baseline: 8.1410x; 2.9684x over previous
//
#include <hip/hip_runtime.h>

// ---------------- problem dims ----------------
constexpr int BB = 16;       // batch
constexpr int TT = 256;      // seq len
constexpr int IN0 = 512;     // input dim (layer 0)
constexpr int HH = 1024;     // hidden
constexpr int GG = 4096;     // 4*H gates
constexpr int NLAYERS = 8;
constexpr int NWG = 256;     // scan workgroups (1 per CU)

// ---------------- ws layout (bytes) ----------------
constexpr size_t XG_OFF  = 0;                        // xg2 [t][b][4096] : 64 MB
constexpr size_t HSA_OFF = 67108864;                 // 16 MB
constexpr size_t HSB_OFF = HSA_OFF + 16777216;       // 16 MB
constexpr size_t HG2_OFF = HSB_OFF + 16777216;       // hglob2 [16 chunk][16 b][64] : 64 KB
constexpr size_t FC1_OFF = HG2_OFF + 65536;          // 32 KB
constexpr size_t FC2_OFF = FC1_OFF + 32768;          // 16 KB
constexpr size_t BAR_OFF = FC2_OFF + 16384;          // barrier state (4 KB)
// bar (unsigned): arrive[g] @ g*16 (g<16); root @ 256; gen copy[g] @ 512+g*16

// ---------------- scan LDS float offsets ----------------
constexpr int WT_F = 0;        // 17440 floats
constexpr int HB_F = 17440;    // 17472 floats
constexpr int PART_F = 34912;  // 1024 floats  [wave][16r][16b]
constexpr int GV_F = 35936;    // 256 floats   [16r][16b]
constexpr int SMEM_FLOATS = 36192;
constexpr int SMEM_BYTES = SMEM_FLOATS * 4;   // 144,768 B

// ---------------- GEMM: xg2[(t*16+b)*4096+n] = X[m]·W[n] + bih[n]+bhh[n], m=b*256+t
__global__ __launch_bounds__(256) void gemm_xg(const float* __restrict__ X,
                                               const float* __restrict__ W,
                                               const float* __restrict__ bih,
                                               const float* __restrict__ bhh,
                                               float* __restrict__ out, int K)
{
    __shared__ float Xs[64][33];
    __shared__ float Ws[64][33];
    const int tid = threadIdx.x;
    const int tm = tid >> 4, tn = tid & 15;
    const int m0 = blockIdx.y * 64, n0 = blockIdx.x * 64;
    float acc[4][4] = {};

    for (int k0 = 0; k0 < K; k0 += 32) {
#pragma unroll
        for (int i = 0; i < 2; ++i) {
            int f = tid + i * 256;
            int row = f >> 3, c4 = (f & 7) << 2;
            float4 xv = *(const float4*)(X + (size_t)(m0 + row) * K + k0 + c4);
            float4 wv = *(const float4*)(W + (size_t)(n0 + row) * K + k0 + c4);
            Xs[row][c4 + 0] = xv.x; Xs[row][c4 + 1] = xv.y;
            Xs[row][c4 + 2] = xv.z; Xs[row][c4 + 3] = xv.w;
            Ws[row][c4 + 0] = wv.x; Ws[row][c4 + 1] = wv.y;
            Ws[row][c4 + 2] = wv.z; Ws[row][c4 + 3] = wv.w;
        }
        __syncthreads();
#pragma unroll 4
        for (int kk = 0; kk < 32; ++kk) {
            float xr[4], wc[4];
#pragma unroll
            for (int i = 0; i < 4; ++i) xr[i] = Xs[tm * 4 + i][kk];
#pragma unroll
            for (int j = 0; j < 4; ++j) wc[j] = Ws[tn * 4 + j][kk];
#pragma unroll
            for (int i = 0; i < 4; ++i)
#pragma unroll
                for (int j = 0; j < 4; ++j)
                    acc[i][j] = fmaf(xr[i], wc[j], acc[i][j]);
        }
        __syncthreads();
    }

    const int n = n0 + tn * 4;
    const float4 bi = *(const float4*)(bih + n);
    const float4 bh = *(const float4*)(bhh + n);
    const float4 bias = {bi.x + bh.x, bi.y + bh.y, bi.z + bh.z, bi.w + bh.w};
#pragma unroll
    for (int i = 0; i < 4; ++i) {
        int m = m0 + tm * 4 + i;
        int bb = m >> 8, tt = m & 255;
        float4 o = {acc[i][0] + bias.x, acc[i][1] + bias.y,
                    acc[i][2] + bias.z, acc[i][3] + bias.w};
        *(float4*)(out + (size_t)(tt * 16 + bb) * GG + n) = o;
    }
}

__device__ __forceinline__ float sigf(float x) { return 1.0f / (1.0f + expf(-x)); }

// ---------------- per-layer LSTM scan (persistent, fence-free sync) ----------------
// WG wg owns h-cols j0=4wg..4wg+3 -> 16 gate rows grow(r)=(r>>2)*1024+j0+(r&3)
// wave w handles k in [256w,256w+256) = chunks 4w..4w+3
__global__ __launch_bounds__(256, 1) void lstm_scan(const float* __restrict__ Whh,
                                                    const float* __restrict__ xg,
                                                    float* __restrict__ hseq,
                                                    float* __restrict__ hglob2,
                                                    unsigned* __restrict__ bar,
                                                    unsigned wantbase)
{
    extern __shared__ float smem[];
    float4* sm4 = (float4*)smem;

    const int tid = threadIdx.x;
    const int wg  = blockIdx.x;
    const int j0  = wg << 2;
    const int w   = tid >> 6;
    const int ln  = tid & 63;

    // ---- stage Whh tile once
    {
        const int r = tid >> 4, m = tid & 15;
        const int grow = ((r >> 2) << 10) + j0 + (r & 3);
        const float4* wsrc = (const float4*)Whh + (size_t)grow * 256 + m;
        float4* wdst = sm4 + r * 272 + 2 * (r >> 2) + m;
#pragma unroll
        for (int q = 0; q < 16; ++q)
            wdst[q * 17] = wsrc[q * 16];
    }

    // lane decomposition for the dot
    const int kg = ln >> 4, rg = (ln >> 2) & 3, bg4 = ln & 3;
    const int blk = (w << 2) + kg;
    int Wb[4], Hb[4];
#pragma unroll
    for (int i = 0; i < 4; ++i)
        Wb[i] = (4 * rg + i) * 272 + 2 * rg + blk * 17;
#pragma unroll
    for (int j = 0; j < 4; ++j)
        Hb[j] = (HB_F >> 2) + blk * 273 + (4 * bg4 + j) * 17;

    const int sb_hi = ln >> 4, sm_lo = ln & 15;

    const int r_red = tid >> 4, b_red = tid & 15;
    const int grow_red = ((r_red >> 2) << 10) + j0 + (r_red & 3);
    const int jl = tid >> 4, bg = tid & 15;      // for tid<64

    // barrier pointers (tid0 use)
    unsigned* arr  = bar + ((wg >> 4) << 4);
    unsigned* root = bar + 256;
    unsigned* genc = bar + 512 + ((wg >> 4) << 4);

    float c_state = 0.0f;
    __syncthreads();

    float xg_pref = xg[(size_t)(0 * 16 + b_red) * GG + grow_red];

    for (int t = 0; t < TT; ++t) {
        float acc[4][4] = {};

        if (t > 0) {
            // h(t-1): device-coherent loads (sc0 sc1) -> regs -> LDS. No fences needed.
            float4 v[4][4];
#pragma unroll
            for (int c = 0; c < 4; ++c) {
                const float4* p = (const float4*)hglob2 + ((w << 2) + c) * 256 + ln;
                asm volatile(
                    "global_load_dwordx4 %0, %4, off sc0 sc1\n\t"
                    "global_load_dwordx4 %1, %4, off offset:1024 sc0 sc1\n\t"
                    "global_load_dwordx4 %2, %4, off offset:2048 sc0 sc1\n\t"
                    "global_load_dwordx4 %3, %4, off offset:3072 sc0 sc1"
                    : "=&v"(v[c][0]), "=&v"(v[c][1]), "=&v"(v[c][2]), "=&v"(v[c][3])
                    : "v"(p) : "memory");
            }
            asm volatile("s_waitcnt vmcnt(0)" ::: "memory");
            __builtin_amdgcn_sched_barrier(0);
#pragma unroll
            for (int c = 0; c < 4; ++c)
#pragma unroll
                for (int i = 0; i < 4; ++i)
                    sm4[(HB_F >> 2) + ((w << 2) + c) * 273 + ((i << 2) + sb_hi) * 17 + sm_lo] = v[c][i];
            asm volatile("s_waitcnt lgkmcnt(0)" ::: "memory");
            __builtin_amdgcn_wave_barrier();

            // ---- dot: 16 k4-iters, 8 b128 reads + 64 fma each
#pragma unroll 4
            for (int k4 = 0; k4 < 16; ++k4) {
                float4 wv[4], hv[4];
#pragma unroll
                for (int i = 0; i < 4; ++i) wv[i] = sm4[Wb[i] + k4];
#pragma unroll
                for (int j = 0; j < 4; ++j) hv[j] = sm4[Hb[j] + k4];
#pragma unroll
                for (int i = 0; i < 4; ++i)
#pragma unroll
                    for (int j = 0; j < 4; ++j) {
                        acc[i][j] = fmaf(wv[i].x, hv[j].x, acc[i][j]);
                        acc[i][j] = fmaf(wv[i].y, hv[j].y, acc[i][j]);
                        acc[i][j] = fmaf(wv[i].z, hv[j].z, acc[i][j]);
                        acc[i][j] = fmaf(wv[i].w, hv[j].w, acc[i][j]);
                    }
            }
            // ---- k-butterfly across kg (lane bits 4,5)
#pragma unroll
            for (int i = 0; i < 4; ++i)
#pragma unroll
                for (int j = 0; j < 4; ++j) {
                    float vv = acc[i][j];
                    vv += __shfl_xor(vv, 16);
                    vv += __shfl_xor(vv, 32);
                    acc[i][j] = vv;
                }
        }

        if (ln < 16) {   // kg==0 lanes hold full per-wave k-slice sums
            const int rg0 = ln >> 2, bg0 = ln & 3;
#pragma unroll
            for (int i = 0; i < 4; ++i)
#pragma unroll
                for (int j = 0; j < 4; ++j)
                    smem[PART_F + (w << 8) + (4 * rg0 + i) * 16 + 4 * bg0 + j] = acc[i][j];
        }
        __syncthreads();

        smem[GV_F + tid] = smem[PART_F + tid] + smem[PART_F + 256 + tid] +
                           smem[PART_F + 512 + tid] + smem[PART_F + 768 + tid] + xg_pref;
        __syncthreads();

        // prefetch next step's xg (hides under gates + barrier)
        float xg_next = 0.f;
        if (t + 1 < TT)
            xg_next = xg[(size_t)((t + 1) * 16 + b_red) * GG + grow_red];

        if (tid < 64) {
            const int col = j0 + jl;
            float iv = smem[GV_F + (jl     ) * 16 + bg];
            float fv = smem[GV_F + (jl +  4) * 16 + bg];
            float gg = smem[GV_F + (jl +  8) * 16 + bg];
            float ov = smem[GV_F + (jl + 12) * 16 + bg];
            c_state = sigf(fv) * c_state + sigf(iv) * tanhf(gg);
            float hval = sigf(ov) * tanhf(c_state);
            // device-coherent scalar store (line-granular, no cache-wide fence)
            float* hdst = hglob2 + ((col >> 6) << 10) + (bg << 6) + (col & 63);
            asm volatile("global_store_dword %0, %1, off sc0 sc1"
                         :: "v"(hdst), "v"(hval) : "memory");
            hseq[(size_t)(bg * TT + t) * HH + col] = hval;   // plain (kernel-end visible)
        }

        if (t < TT - 1) {
            const unsigned target = wantbase + (unsigned)t + 1u;
            if (tid == 0) {
                // release: h stores (same wave 0) acked at coherence point before arrive
                asm volatile("s_waitcnt vmcnt(0)" ::: "memory");
                unsigned a = __hip_atomic_fetch_add(arr, 1u, __ATOMIC_RELAXED, __HIP_MEMORY_SCOPE_AGENT);
                if (a == 15u) {
                    unsigned ra = __hip_atomic_fetch_add(root, 1u, __ATOMIC_RELAXED, __HIP_MEMORY_SCOPE_AGENT);
                    if (ra == 15u) {
                        __hip_atomic_store(root, 0u, __ATOMIC_RELAXED, __HIP_MEMORY_SCOPE_AGENT);
#pragma unroll
                        for (int i = 0; i < 16; ++i)
                            __hip_atomic_store(bar + (i << 4), 0u, __ATOMIC_RELAXED, __HIP_MEMORY_SCOPE_AGENT);
                        // resets must land before gen publish (separate lines)
                        asm volatile("s_waitcnt vmcnt(0)" ::: "memory");
#pragma unroll
                        for (int i = 0; i < 16; ++i)
                            __hip_atomic_store(bar + 512 + (i << 4), target,
                                               __ATOMIC_RELAXED, __HIP_MEMORY_SCOPE_AGENT);
                    }
                }
                while (__hip_atomic_load(genc, __ATOMIC_RELAXED, __HIP_MEMORY_SCOPE_AGENT) < target)
                    __builtin_amdgcn_s_sleep(1);
            }
            __syncthreads();
        }
        xg_pref = xg_next;
    }
}

// ---------------- FC head ----------------
__global__ void fc_relu(const float* __restrict__ in, const float* __restrict__ w,
                        const float* __restrict__ b, float* __restrict__ out,
                        int N, int K, int instride, int do_relu)
{
    int g = blockIdx.x * blockDim.x + threadIdx.x;
    if (g >= BB * N) return;
    int bi = g / N, n = g - bi * N;
    const float* ip = in + (size_t)bi * instride;
    const float* wp = w + (size_t)n * K;
    float s = 0.f;
    for (int k = 0; k < K; k += 4) {
        float4 a = *(const float4*)(ip + k);
        float4 q = *(const float4*)(wp + k);
        s += a.x * q.x + a.y * q.y + a.z * q.z + a.w * q.w;
    }
    s += b[n];
    if (do_relu) s = fmaxf(s, 0.f);
    out[g] = s;
}

// ---------------- launch ----------------
extern "C" void kernel_launch(void* const* d_in, const int* in_sizes, int n_in,
                              void* d_out, int out_size, void* d_ws, size_t ws_size,
                              hipStream_t stream)
{
    const float* x    = (const float*)d_in[0];
    const float* Wih0 = (const float*)d_in[1];
    const float* WihR = (const float*)d_in[2];
    const float* Whh  = (const float*)d_in[3];
    const float* bih  = (const float*)d_in[4];
    const float* bhh  = (const float*)d_in[5];
    const float* fc1w = (const float*)d_in[6];
    const float* fc1b = (const float*)d_in[7];
    const float* fc2w = (const float*)d_in[8];
    const float* fc2b = (const float*)d_in[9];
    const float* fc3w = (const float*)d_in[10];
    const float* fc3b = (const float*)d_in[11];
    float* out = (float*)d_out;
    char* ws = (char*)d_ws;

    float* xg     = (float*)(ws + XG_OFF);
    float* hsA    = (float*)(ws + HSA_OFF);
    float* hsB    = (float*)(ws + HSB_OFF);
    float* hglob2 = (float*)(ws + HG2_OFF);
    float* fc1o   = (float*)(ws + FC1_OFF);
    float* fc2o   = (float*)(ws + FC2_OFF);
    unsigned* bar = (unsigned*)(ws + BAR_OFF);

    (void)hipFuncSetAttribute((const void*)lstm_scan,
                              hipFuncAttributeMaxDynamicSharedMemorySize, SMEM_BYTES);
    (void)hipMemsetAsync(ws + BAR_OFF, 0, 4096, stream);   // arrive/root/gen = 0 (monotonic)

    for (int l = 0; l < NLAYERS; ++l) {
        const float* X  = (l == 0) ? x : ((l & 1) ? hsA : hsB);
        const int K     = (l == 0) ? IN0 : HH;
        const float* Wl = (l == 0) ? Wih0 : (WihR + (size_t)(l - 1) * GG * HH);
        gemm_xg<<<dim3(GG / 64, (BB * TT) / 64), 256, 0, stream>>>(
            X, Wl, bih + (size_t)l * GG, bhh + (size_t)l * GG, xg, K);

        float* hout = (l & 1) ? hsB : hsA;
        const float* whh_l = Whh + (size_t)l * GG * HH;
        unsigned wantbase = (unsigned)(TT * l);
        void* args[6] = {(void*)&whh_l, (void*)&xg, (void*)&hout,
                         (void*)&hglob2, (void*)&bar, (void*)&wantbase};
        hipError_t e = hipLaunchCooperativeKernel((void*)lstm_scan, dim3(NWG), dim3(256),
                                                  args, SMEM_BYTES, stream);
        if (e != hipSuccess) {
            lstm_scan<<<dim3(NWG), dim3(256), SMEM_BYTES, stream>>>(
                whh_l, xg, hout, hglob2, bar, wantbase);
        }
    }

    const float* hlast = hsB + (size_t)255 * HH;
    fc_relu<<<32, 256, 0, stream>>>(hlast, fc1w, fc1b, fc1o, 512, 1024, TT * HH, 1);
    fc_relu<<<16, 256, 0, stream>>>(fc1o, fc2w, fc2b, fc2o, 256, 512, 512, 1);
    fc_relu<<<1, 16, 0, stream>>>(fc2o, fc3w, fc3b, out, 1, 256, 256, 0);
}